// Round 13
// baseline (120.176 us; speedup 1.0000x reference)
//
#include <hip/hip_runtime.h>

// B=8, T=2048, C=768, HS=64. fp32 in/out; bf16 MFMA internally.
// R21 = R20 with PHASE C de-LDS'd (same playbook that won R20 for phase B):
// phase B's epilogue now stores q AND k in MFMA A-FRAG ORDER (it already
// stages them in LDS, so reordering the final stores is free). Phase C then
// loads Q/K/V straight into registers as contiguous 1KB frag chunks --
// the per-visit loop has ZERO LDS ops (was 4 ds_write + 4 ds_read + commit).
// K and V ping-pong (kc/kn, vc/vn; static-index copies) with a full visit
// of latency cover. Values bit-identical; only storage order changed.

typedef short bf16x8 __attribute__((ext_vector_type(8)));  // 8 bf16 = 4 VGPR
typedef short bf16x4 __attribute__((ext_vector_type(4)));  // 4 bf16 = 2 VGPR
typedef float f32x4  __attribute__((ext_vector_type(4)));
typedef unsigned u32x2 __attribute__((ext_vector_type(2)));
typedef unsigned u32x4 __attribute__((ext_vector_type(4)));

#define MFMA_BF16(a, b, c) __builtin_amdgcn_mfma_f32_16x16x32_bf16((a), (b), (c), 0, 0, 0)

#if __has_builtin(__builtin_amdgcn_mfma_f32_16x16x16bf16_1k)
#define HAVE_MFMA16 1
#define MFMA16(a, b, c) __builtin_amdgcn_mfma_f32_16x16x16bf16_1k((a), (b), (c), 0, 0, 0)
#else
#define HAVE_MFMA16 0
#endif

// scale = C^-0.5 * log2(e), folded into Wq at prep time
#define SCALE_LOG2E 0.05206626f

__device__ __forceinline__ unsigned rbf(float f) {  // RNE bf16 in high 16 bits
  unsigned u = __builtin_bit_cast(unsigned, f);
  return u + 0x7fffu + ((u >> 16) & 1u);
}
__device__ __forceinline__ short f2bf(float f) { return (short)(rbf(f) >> 16); }
__device__ __forceinline__ unsigned pkbf(float a, float b) {  // [lo=a, hi=b]
  return (rbf(a) >> 16) | (rbf(b) & 0xFFFF0000u);
}
__device__ __forceinline__ float bsum(unsigned dw) {  // sum of 2 packed bf16
  float lo = __builtin_bit_cast(float, dw << 16);
  float hi = __builtin_bit_cast(float, dw & 0xFFFF0000u);
  return lo + hi;
}

// System-scope write-through store (gfx950 spellings: sc0 sc1). Data reaches
// the MALL coherence point; no dirty L2 lines -> fence-free grid barrier.
__device__ __forceinline__ void st16_sys(void* p, u32x4 v) {
  asm volatile("global_store_dwordx4 %0, %1, off sc0 sc1" ::"v"(p), "v"(v)
               : "memory");
}

// Fence-free two-level grid barrier (R18). Drain own stores -> block barrier
// -> striped device-scope arrive -> block 0 aggregates and publishes `rel`;
// others poll the single release word. Timeout failsafes keep failure mode =
// visible wrong answer, never a hang.
__device__ __forceinline__ void gbar(unsigned* ctr, unsigned* rel,
                                     unsigned target) {
  asm volatile("s_waitcnt vmcnt(0)" ::: "memory");
  __syncthreads();
  if (threadIdx.x == 0) {
    atomicAdd(&ctr[(blockIdx.x & 63) * 32], 1u);
    long long t0 = (long long)__builtin_amdgcn_s_memtime();
    if (blockIdx.x == 0) {
      for (;;) {
        unsigned s = 0;
#pragma unroll
        for (int i = 0; i < 64; ++i)
          s += __hip_atomic_load(&ctr[i * 32], __ATOMIC_RELAXED,
                                 __HIP_MEMORY_SCOPE_AGENT);
        if (s >= target) break;
        __builtin_amdgcn_s_sleep(2);
        if ((long long)__builtin_amdgcn_s_memtime() - t0 > (1LL << 28)) break;
      }
      __hip_atomic_store(rel, 1u, __ATOMIC_RELAXED, __HIP_MEMORY_SCOPE_AGENT);
    } else {
      while (__hip_atomic_load(rel, __ATOMIC_RELAXED,
                               __HIP_MEMORY_SCOPE_AGENT) == 0) {
        __builtin_amdgcn_s_sleep(16);
        if ((long long)__builtin_amdgcn_s_memtime() - t0 > (1LL << 28)) break;
      }
    }
    asm volatile("" ::: "memory");  // keep later loads below the poll
  }
  __syncthreads();
}

// ---------------------------------------------------------------------------
// Fused kernel. 512 blocks x 256 threads, plain launch.
// Buffers (frag order = [b][v][frag 0..3][lane 0..63][8 bf16], 2KB/visit):
//   qfb: frag (qs,c)   -> Q[v*32+16qs+col][32c+8quad+j]   (pre-scaled)
//   kfb: frag (t,h)    -> K[v*32+16t+col][32h+8quad+j]
//   vfb: MFMA16 A-frag (unchanged)
// LDS union (49664 B = 24832 shorts):
//   B: xs[32][776] bf16 x-tile (staged once, read-only)
//   B epilogue: qk[32][136] (rows 272B: 16B-aligned, ~2-way banks)
//   C: combine overlay 6912 floats (27648 B)
// Co-residency: __launch_bounds__(256,2) + 49.7 KB LDS -> 2 blocks/CU.
// ---------------------------------------------------------------------------
__global__ __launch_bounds__(256, 2) void fused_kernel(
    const float* __restrict__ x, const float* __restrict__ Wk,
    const float* __restrict__ Wq, const float* __restrict__ Wv,
    short* __restrict__ wtf, short* __restrict__ qfb, short* __restrict__ kfb,
    short* __restrict__ vfb, unsigned* __restrict__ bar,
    float* __restrict__ out) {
  __shared__ __attribute__((aligned(16))) short lds[24832];

  const int tid  = threadIdx.x;
  const int wave = tid >> 6;
  const int lane = tid & 63;
  const int quad = lane >> 4;
  const int col  = lane & 15;

  // ============== phase A: prep wtf (B-fragment-order weights) =============
  {
    int gid = blockIdx.x * 256 + tid;
    if (gid < 24 * 12 * 64) {
      int ks   = gid / 768;
      int rem  = gid - ks * 768;
      int nt   = rem >> 6;
      int pl   = rem & 63;
      int pq = pl >> 4, pc = pl & 15;
      const float* W = (nt < 4) ? Wq : (nt < 8) ? Wk : Wv;
      float s = (nt < 4) ? SCALE_LOG2E : 1.0f;
      int h  = (nt & 3) * 16 + pc;
      int k0 = ks * 32 + pq * 8;
      bf16x8 v;
#pragma unroll
      for (int j = 0; j < 8; ++j) v[j] = f2bf(W[(k0 + j) * 64 + h] * s);
      st16_sys(wtf + (size_t)gid * 8, __builtin_bit_cast(u32x4, v));
    }
  }
  gbar(bar, bar + 128 * 32, 512);

  // ============== phase B: projections (x-in-LDS, zero-barrier loop) =======
  {
    short* xs = lds;  // [32][776] bf16, row stride 776 (rows 16B-aligned)

    const int msub = wave >> 1;
    const int nh   = wave & 1;
    const int m0   = blockIdx.x * 32;

    // ---- stage x tile once: 32 rows x 768 fp32 -> bf16 ----
#pragma unroll 4
    for (int it = 0; it < 24; ++it) {
      int f   = tid + it * 256;        // [0, 6144)
      int row = f / 192, c4 = f - row * 192;
      float4 xv = *(const float4*)(x + (size_t)(m0 + row) * 768 + c4 * 4);
      unsigned lo = pkbf(xv.x, xv.y);
      unsigned hi = pkbf(xv.z, xv.w);
      *(uint2*)&xs[row * 776 + c4 * 4] = make_uint2(lo, hi);
    }
    __syncthreads();

    // ---- MFMA loop: B-frags straight from wtf, double-buffered ----
    f32x4 acc[6];
#pragma unroll
    for (int i = 0; i < 6; ++i) acc[i] = (f32x4){0.f, 0.f, 0.f, 0.f};

    auto ldw = [&](int ks, bf16x8* dst) {
      const short* p = wtf + (size_t)ks * 6144 + ((nh * 6) * 64 + lane) * 8;
#pragma unroll
      for (int i = 0; i < 6; ++i) dst[i] = *(const bf16x8*)(p + i * 512);
    };
    auto lda = [&](int ks) {
      return *(const bf16x8*)&xs[(msub * 16 + col) * 776 + ks * 32 + quad * 8];
    };

    bf16x8 bc[6], bn[6];
    ldw(0, bc);
    bf16x8 af = lda(0);
    for (int ks = 0; ks < 24; ++ks) {
      if (ks + 1 < 24) ldw(ks + 1, bn);
      bf16x8 afn = (ks + 1 < 24) ? lda(ks + 1) : af;
#pragma unroll
      for (int i = 0; i < 6; ++i) acc[i] = MFMA_BF16(af, bc[i], acc[i]);
#pragma unroll
      for (int i = 0; i < 6; ++i) bc[i] = bn[i];
      af = afn;
    }

    // ---- epilogue: acc C/D col=lane&15, row=quad*4+rr. Stage q/k through
    // LDS tile qk[32][136] (q cols 0-63, k cols 64-127), then emit BOTH in
    // A-frag order (2KB each): frag seg=(fs,fc), lane(q2,c2) <-
    //   q: qk[16*fs+c2][32*fc+8*q2+..]; k: +64. V unchanged (already frag).
    const int b = m0 >> 11;
    const int v = (m0 & 2047) >> 5;  // 32-key visit within batch

    __syncthreads();     // all waves past their last xs reads
    short* qk = lds;     // [32][136], overlays xs
#pragma unroll
    for (int i = 0; i < 6; ++i) {
      int nt = nh * 6 + i;
      if (nt < 8) {
        int cb = ((nt < 4) ? 0 : 64) + (nt & 3) * 16 + col;
        int r0 = msub * 16 + quad * 4;
#pragma unroll
        for (int r = 0; r < 4; ++r) qk[(r0 + r) * 136 + cb] = f2bf(acc[i][r]);
      }
    }
    if (nh == 1) {
      // V (acc[2..5]): pack straight into MFMA16 A-frag order.
#pragma unroll
      for (int pg = 0; pg < 2; ++pg) {
        unsigned w0 = pkbf(acc[2 + 2 * pg][0], acc[2 + 2 * pg][1]);
        unsigned w1 = pkbf(acc[2 + 2 * pg][2], acc[2 + 2 * pg][3]);
        unsigned w2 = pkbf(acc[3 + 2 * pg][0], acc[3 + 2 * pg][1]);
        unsigned w3 = pkbf(acc[3 + 2 * pg][2], acc[3 + 2 * pg][3]);
        u32x4 pu = {w0, w1, w2, w3};
        st16_sys(vfb + ((size_t)((b * 64 + v) * 4 + msub * 2 + pg)) * 512 + lane * 8,
                 pu);
      }
    }
    __syncthreads();
    {
      const int seg = tid >> 6;          // frag index: fs=seg>>1, fc=seg&1
      const int c2  = lane & 15, q2 = lane >> 4;
      const short* src = &qk[(16 * (seg >> 1) + c2) * 136 + 32 * (seg & 1) + 8 * q2];
      const size_t fbase = ((size_t)((b * 64 + v) * 4 + seg)) * 512 + lane * 8;
      st16_sys(qfb + fbase, *(const u32x4*)src);        // q frag
      st16_sys(kfb + fbase, *(const u32x4*)(src + 64)); // k frag
    }
  }
  gbar(bar + 64 * 32, bar + 128 * 32 + 32, 512);

  // ============== phase C: flash attention (zero-LDS visit loop) ===========
  {
    const int bx = blockIdx.x;
    const int b  = bx & 7;
    // Persistent placement pairs bx with bx+256 on one CU; map qt so each
    // pair is (qt, 63-qt): constant work per CU (perf-only heuristic).
    const int qt = (bx < 256) ? (63 - (bx >> 3)) : ((bx - 256) >> 3);
    const size_t qbase = (size_t)b * 2048 + qt * 32;
    (void)qbase;

    // Q frags direct from qfb (frag order, 1KB contiguous each)
    const short* qP = qfb + ((size_t)(b * 64 + qt) * 4) * 512 + lane * 8;
    bf16x8 qf[2][2];
#pragma unroll
    for (int qs = 0; qs < 2; ++qs)
#pragma unroll
      for (int c = 0; c < 2; ++c)
        qf[qs][c] = *(const bf16x8*)(qP + (qs * 2 + c) * 512);

    f32x4 o[2][4];  // O^T accumulators: [qs][ht], row=h_local, col=q
#pragma unroll
    for (int qs = 0; qs < 2; ++qs)
#pragma unroll
      for (int ht = 0; ht < 4; ++ht) o[qs][ht] = (f32x4){0.f, 0.f, 0.f, 0.f};
    float osum[2] = {0.f, 0.f};

    const int nv = qt + 1;  // 32-key visits; wave w takes w, w+4, ...
    const int mycount = (nv > wave) ? ((nv - wave + 3) >> 2) : 0;

    const short* kB = kfb + (size_t)b * 64 * 4 * 512;
    const short* vB = vfb + (size_t)b * 64 * 4 * 512;

    bf16x8 kc[4], kn[4], vc[4], vn[4];
    auto issue_k = [&](int v, bf16x8* dst) {  // frag-order, 1KB/load
      const short* p = kB + (size_t)v * 4 * 512 + lane * 8;
#pragma unroll
      for (int g = 0; g < 4; ++g) dst[g] = *(const bf16x8*)(p + g * 512);
    };
    auto issue_v = [&](int v, bf16x8* dst) {
      const short* p = vB + (size_t)v * 4 * 512 + lane * 8;
#pragma unroll
      for (int g = 0; g < 4; ++g) dst[g] = *(const bf16x8*)(p + g * 512);
    };
    if (mycount > 0) { issue_k(wave, kc); issue_v(wave, vc); }

    for (int i = 0; i < mycount; ++i) {
      const int v = wave + i * 4;

      if (i + 1 < mycount) { issue_k(v + 4, kn); issue_v(v + 4, vn); }

      // ---- S^T = K Q^T : A=K frags (regs, kc), B=Q (regs) ----
      f32x4 st[2][2];  // [qs][t: 16-key tile]
#pragma unroll
      for (int qs = 0; qs < 2; ++qs)
#pragma unroll
        for (int t = 0; t < 2; ++t) st[qs][t] = (f32x4){0.f, 0.f, 0.f, 0.f};
#pragma unroll
      for (int t = 0; t < 2; ++t)
#pragma unroll
        for (int qs = 0; qs < 2; ++qs) {
          st[qs][t] = MFMA_BF16(kc[t * 2 + 0], qf[qs][0], st[qs][t]);
          st[qs][t] = MFMA_BF16(kc[t * 2 + 1], qf[qs][1], st[qs][t]);
        }

      // ---- p = exp2(s); causal mask on diagonal visit ----
      const bool diag = (v == qt);  // wave-uniform
      unsigned d[2][2][2];          // packed bf16 P: [qs][t][pair]
#pragma unroll
      for (int qs = 0; qs < 2; ++qs) {
        float part = 0.f;
#pragma unroll
        for (int t = 0; t < 2; ++t) {
          float pr[4];
#pragma unroll
          for (int rr = 0; rr < 4; ++rr) {
            float sv = st[qs][t][rr];
            if (diag && (t * 16 + quad * 4 + rr) > (qs * 16 + col)) sv = -1e30f;
            pr[rr] = __builtin_amdgcn_exp2f(sv);
          }
          d[qs][t][0] = pkbf(pr[0], pr[1]);
          d[qs][t][1] = pkbf(pr[2], pr[3]);
          part += bsum(d[qs][t][0]) + bsum(d[qs][t][1]);
        }
        part += __shfl_xor(part, 16);
        part += __shfl_xor(part, 32);
        osum[qs] += part;
      }

#if HAVE_MFMA16
      // ---- O^T += V^T P^T : V frags from vc regs, P from d regs ----
#pragma unroll
      for (int t = 0; t < 2; ++t)
#pragma unroll
        for (int pg = 0; pg < 2; ++pg) {
          uint4 u = __builtin_bit_cast(uint4, vc[t * 2 + pg]);
          u32x2 l2 = {u.x, u.y}, h2 = {u.z, u.w};
          bf16x4 vlo = __builtin_bit_cast(bf16x4, l2);  // ht = 2*pg
          bf16x4 vhi = __builtin_bit_cast(bf16x4, h2);  // ht = 2*pg+1
#pragma unroll
          for (int qs = 0; qs < 2; ++qs) {
            u32x2 pd = {d[qs][t][0], d[qs][t][1]};
            bf16x4 pb = __builtin_bit_cast(bf16x4, pd);
            o[qs][2 * pg]     = MFMA16(vlo, pb, o[qs][2 * pg]);
            o[qs][2 * pg + 1] = MFMA16(vhi, pb, o[qs][2 * pg + 1]);
          }
        }
#else
      // ---- fallback: shfl-transpose P (K=32) + shfl-gather V bf16x8 ----
      bf16x8 pbf[2];
#pragma unroll
      for (int qs = 0; qs < 2; ++qs) {
        unsigned dA0 = d[qs][0][0], dB0 = d[qs][0][1];
        unsigned dA1 = d[qs][1][0], dB1 = d[qs][1][1];
        int base = ((quad & 1) << 5) + col;
        unsigned a0  = __shfl(dA0, base),      a1  = __shfl(dA1, base);
        unsigned b0  = __shfl(dB0, base),      b1  = __shfl(dB1, base);
        unsigned a0h = __shfl(dA0, base + 16), a1h = __shfl(dA1, base + 16);
        unsigned b0h = __shfl(dB0, base + 16), b1h = __shfl(dB1, base + 16);
        bool hi = quad >= 2;
        uint4 pu = make_uint4(hi ? a1 : a0, hi ? b1 : b0,
                              hi ? a1h : a0h, hi ? b1h : b0h);
        pbf[qs] = __builtin_bit_cast(bf16x8, pu);
      }
#pragma unroll
      for (int ht = 0; ht < 4; ++ht) {
        int pg = ht >> 1;
        bool odd = ht & 1;
        int L0 = ((quad & 1) * 2) * 16 + col, L1 = L0 + 16;
        uint4 u0 = __builtin_bit_cast(uint4, vc[pg]);
        uint4 u1 = __builtin_bit_cast(uint4, vc[2 + pg]);
        unsigned s0 = odd ? u0.z : u0.x, s1 = odd ? u0.w : u0.y;
        unsigned s2 = odd ? u1.z : u1.x, s3 = odd ? u1.w : u1.y;
        unsigned d0a = __shfl(s0, L0), d1a = __shfl(s1, L0);
        unsigned d2a = __shfl(s0, L1), d3a = __shfl(s1, L1);
        unsigned d0b = __shfl(s2, L0), d1b = __shfl(s3, L0);
        unsigned d2b = __shfl(s2, L1), d3b = __shfl(s3, L1);
        bool t1 = quad >= 2;
        uint4 vu = make_uint4(t1 ? d0b : d0a, t1 ? d1b : d1a,
                              t1 ? d2b : d2a, t1 ? d3b : d3a);
        bf16x8 vf8 = __builtin_bit_cast(bf16x8, vu);
#pragma unroll
        for (int qs = 0; qs < 2; ++qs)
          o[qs][ht] = MFMA_BF16(vf8, pbf[qs], o[qs][ht]);
      }
#endif
      if (i + 1 < mycount) {  // promote prefetch (static indices only)
#pragma unroll
        for (int g = 0; g < 4; ++g) { kc[g] = kn[g]; vc[g] = vn[g]; }
      }
    }

    // ---- 4-way split-K combine (pure fp32 add; no-max softmax) ----
    __syncthreads();
    float* comb = (float*)lds;
    if (wave > 0) {
      float* p = comb + ((wave - 1) * 64 + lane) * 36;
#pragma unroll
      for (int qs = 0; qs < 2; ++qs)
#pragma unroll
        for (int ht = 0; ht < 4; ++ht)
          *(f32x4*)(p + (qs * 4 + ht) * 4) = o[qs][ht];
      p[32] = osum[0];
      p[33] = osum[1];
    }
    __syncthreads();
    if (wave == 0) {
#pragma unroll
      for (int w = 1; w < 4; ++w) {
        const float* p = comb + ((w - 1) * 64 + lane) * 36;
#pragma unroll
        for (int qs = 0; qs < 2; ++qs)
#pragma unroll
          for (int ht = 0; ht < 4; ++ht)
            o[qs][ht] += *(const f32x4*)(p + (qs * 4 + ht) * 4);
        osum[0] += p[32];
        osum[1] += p[33];
      }
      // ---- epilogue: O^T C-layout -> packed float4 stores ----
      const size_t qb0 = (size_t)b * 2048 + qt * 32;
#pragma unroll
      for (int qs = 0; qs < 2; ++qs) {
        float inv = 1.0f / osum[qs];
#pragma unroll
        for (int ht = 0; ht < 4; ++ht) {
          f32x4 val = o[qs][ht];
#pragma unroll
          for (int rr = 0; rr < 4; ++rr) val[rr] *= inv;
          *(f32x4*)(out + (qb0 + qs * 16 + col) * 64 + ht * 16 + quad * 4) = val;
        }
      }
    }
  }
}

// ---------------------------------------------------------------------------
extern "C" void kernel_launch(void* const* d_in, const int* in_sizes, int n_in,
                              void* d_out, int out_size, void* d_ws, size_t ws_size,
                              hipStream_t stream) {
  const float* x  = (const float*)d_in[0];
  const float* Wk = (const float*)d_in[1];
  const float* Wq = (const float*)d_in[2];
  const float* Wv = (const float*)d_in[3];
  float* out = (float*)d_out;

  char* ws = (char*)d_ws;
  // ws layout: wtf (294912 B) | qfb 2MB | kfb 2MB | vfb 2MB | ... | bar @ 8MB
  // bar: 2 barriers x 64 stripes x 128 B + 2 release words (zeroed below).
  short* wtf = (short*)(ws);
  short* qfb = (short*)(ws + (512 << 10));
  short* kfb = (short*)(ws + (512 << 10) + (2 << 20));
  short* vfb = (short*)(ws + (512 << 10) + (4 << 20));
  unsigned* bar = (unsigned*)(ws + (8 << 20));

  hipMemsetAsync(bar, 0, 20480, stream);  // zero stripes + release words
  fused_kernel<<<512, 256, 0, stream>>>(x, Wk, Wq, Wv, wtf, qfb, kfb, vfb,
                                        bar, out);
}

// Round 14
// 118.355 us; speedup vs baseline: 1.0154x; 1.0154x over previous
//
#include <hip/hip_runtime.h>

// B=8, T=2048, C=768, HS=64. fp32 in/out; bf16 MFMA internally.
// R22 = R20 (best, 118.4us) + 512-THREAD blocks for 2x occupancy.
// Diagnosis: Occupancy ~17% (2 waves/SIMD) -- every phase latency-bound with
// no TLP; phase C tail = qt=63 block's 16-visit chain (2x grid average).
// Change: 512 blocks x 512 threads (16 waves/CU, co-residency kept: LDS
// 49.7KBx2<=160KB, VGPR<=128, 16<=32 waves). A/B semantics unchanged
// (staging uses all 8 waves; MFMA+epilogue gated wave<4; B's loop is
// barrier-free so gating is sync-safe). Phase C: 8-way split-K (R11-proven),
// chain 16->8 visits + 2x TLP; combine = fold 8->4 (36.9KB slots) then 4->1.

typedef short bf16x8 __attribute__((ext_vector_type(8)));  // 8 bf16 = 4 VGPR
typedef short bf16x4 __attribute__((ext_vector_type(4)));  // 4 bf16 = 2 VGPR
typedef float f32x4  __attribute__((ext_vector_type(4)));
typedef unsigned u32x2 __attribute__((ext_vector_type(2)));
typedef unsigned u32x4 __attribute__((ext_vector_type(4)));

#define MFMA_BF16(a, b, c) __builtin_amdgcn_mfma_f32_16x16x32_bf16((a), (b), (c), 0, 0, 0)

#if __has_builtin(__builtin_amdgcn_mfma_f32_16x16x16bf16_1k)
#define HAVE_MFMA16 1
#define MFMA16(a, b, c) __builtin_amdgcn_mfma_f32_16x16x16bf16_1k((a), (b), (c), 0, 0, 0)
#else
#define HAVE_MFMA16 0
#endif

// scale = C^-0.5 * log2(e), folded into Wq at prep time
#define SCALE_LOG2E 0.05206626f

__device__ __forceinline__ unsigned rbf(float f) {  // RNE bf16 in high 16 bits
  unsigned u = __builtin_bit_cast(unsigned, f);
  return u + 0x7fffu + ((u >> 16) & 1u);
}
__device__ __forceinline__ short f2bf(float f) { return (short)(rbf(f) >> 16); }
__device__ __forceinline__ unsigned pkbf(float a, float b) {  // [lo=a, hi=b]
  return (rbf(a) >> 16) | (rbf(b) & 0xFFFF0000u);
}
__device__ __forceinline__ float bsum(unsigned dw) {  // sum of 2 packed bf16
  float lo = __builtin_bit_cast(float, dw << 16);
  float hi = __builtin_bit_cast(float, dw & 0xFFFF0000u);
  return lo + hi;
}

// System-scope write-through store (gfx950 spellings: sc0 sc1). Data reaches
// the MALL coherence point; no dirty L2 lines -> fence-free grid barrier.
__device__ __forceinline__ void st16_sys(void* p, u32x4 v) {
  asm volatile("global_store_dwordx4 %0, %1, off sc0 sc1" ::"v"(p), "v"(v)
               : "memory");
}

// Fence-free two-level grid barrier (R18). Drain own stores -> block barrier
// -> striped device-scope arrive -> block 0 aggregates and publishes `rel`;
// others poll the single release word. Timeout failsafes keep failure mode =
// visible wrong answer, never a hang.
__device__ __forceinline__ void gbar(unsigned* ctr, unsigned* rel,
                                     unsigned target) {
  asm volatile("s_waitcnt vmcnt(0)" ::: "memory");
  __syncthreads();
  if (threadIdx.x == 0) {
    atomicAdd(&ctr[(blockIdx.x & 63) * 32], 1u);
    long long t0 = (long long)__builtin_amdgcn_s_memtime();
    if (blockIdx.x == 0) {
      for (;;) {
        unsigned s = 0;
#pragma unroll
        for (int i = 0; i < 64; ++i)
          s += __hip_atomic_load(&ctr[i * 32], __ATOMIC_RELAXED,
                                 __HIP_MEMORY_SCOPE_AGENT);
        if (s >= target) break;
        __builtin_amdgcn_s_sleep(2);
        if ((long long)__builtin_amdgcn_s_memtime() - t0 > (1LL << 28)) break;
      }
      __hip_atomic_store(rel, 1u, __ATOMIC_RELAXED, __HIP_MEMORY_SCOPE_AGENT);
    } else {
      while (__hip_atomic_load(rel, __ATOMIC_RELAXED,
                               __HIP_MEMORY_SCOPE_AGENT) == 0) {
        __builtin_amdgcn_s_sleep(16);
        if ((long long)__builtin_amdgcn_s_memtime() - t0 > (1LL << 28)) break;
      }
    }
    asm volatile("" ::: "memory");  // keep later loads below the poll
  }
  __syncthreads();
}

// ---------------------------------------------------------------------------
// Fused kernel. 512 blocks x 512 threads, plain launch.
// LDS union (49664 B = 24832 shorts):
//   B: xs[32][776] bf16 x-tile (staged once by all 8 waves, read by 4)
//   B epilogue: qk[32][128] = shorts [0,4096)  (xs dead)
//   C: ksw 8 waves x 2304 shorts = [0,18432) ; combine 4 slots (36864 B)
// Co-residency: __launch_bounds__(512,4) (<=128 VGPR -> 4 waves/EU) + 49.7 KB
// LDS (2x = 99 KB < 160 KB) -> 2 blocks/CU x 256 CU = 512 = grid.
// ---------------------------------------------------------------------------
__global__ __launch_bounds__(512, 4) void fused_kernel(
    const float* __restrict__ x, const float* __restrict__ Wk,
    const float* __restrict__ Wq, const float* __restrict__ Wv,
    short* __restrict__ wtf, short* __restrict__ qb, short* __restrict__ kb,
    short* __restrict__ vfb, unsigned* __restrict__ bar,
    float* __restrict__ out) {
  __shared__ __attribute__((aligned(16))) short lds[24832];

  const int tid  = threadIdx.x;
  const int wave = tid >> 6;
  const int lane = tid & 63;
  const int quad = lane >> 4;
  const int col  = lane & 15;

  // ============== phase A: prep wtf (B-fragment-order weights) =============
  // wtf[ks 0..23][nt 0..11][lane 0..63][8 bf16]; nt 0-3 Wq (pre-scaled),
  // 4-7 Wk, 8-11 Wv.
  {
    int gid = blockIdx.x * 512 + tid;
    if (gid < 24 * 12 * 64) {
      int ks   = gid / 768;
      int rem  = gid - ks * 768;
      int nt   = rem >> 6;
      int pl   = rem & 63;
      int pq = pl >> 4, pc = pl & 15;
      const float* W = (nt < 4) ? Wq : (nt < 8) ? Wk : Wv;
      float s = (nt < 4) ? SCALE_LOG2E : 1.0f;
      int h  = (nt & 3) * 16 + pc;
      int k0 = ks * 32 + pq * 8;
      bf16x8 v;
#pragma unroll
      for (int j = 0; j < 8; ++j) v[j] = f2bf(W[(k0 + j) * 64 + h] * s);
      st16_sys(wtf + (size_t)gid * 8, __builtin_bit_cast(u32x4, v));
    }
  }
  gbar(bar, bar + 128 * 32, 512);

  // ============== phase B: projections (x-in-LDS, zero-barrier loop) =======
  {
    short* xs = lds;  // [32][776] bf16, row stride 776 (rows 16B-aligned)

    const int msub = wave >> 1;   // valid for wave<4 (MFMA waves)
    const int nh   = wave & 1;
    const int m0   = blockIdx.x * 32;

    // ---- stage x tile once (ALL 8 waves): 32 x 768 fp32 -> bf16 ----
#pragma unroll 4
    for (int it = 0; it < 12; ++it) {
      int f   = tid + it * 512;        // [0, 6144)
      int row = f / 192, c4 = f - row * 192;
      float4 xv = *(const float4*)(x + (size_t)(m0 + row) * 768 + c4 * 4);
      unsigned lo = pkbf(xv.x, xv.y);
      unsigned hi = pkbf(xv.z, xv.w);
      *(uint2*)&xs[row * 776 + c4 * 4] = make_uint2(lo, hi);
    }
    __syncthreads();

    // ---- MFMA loop (waves 0-3 only; barrier-free): B-frags straight from
    // wtf (frag order, L2-resident), double-buffered one k-step ahead. ----
    f32x4 acc[6];
#pragma unroll
    for (int i = 0; i < 6; ++i) acc[i] = (f32x4){0.f, 0.f, 0.f, 0.f};

    if (wave < 4) {
      auto ldw = [&](int ks, bf16x8* dst) {
        const short* p = wtf + (size_t)ks * 6144 + ((nh * 6) * 64 + lane) * 8;
#pragma unroll
        for (int i = 0; i < 6; ++i) dst[i] = *(const bf16x8*)(p + i * 512);
      };
      auto lda = [&](int ks) {
        return *(const bf16x8*)&xs[(msub * 16 + col) * 776 + ks * 32 + quad * 8];
      };

      bf16x8 bc[6], bn[6];
      ldw(0, bc);
      bf16x8 af = lda(0);
      for (int ks = 0; ks < 24; ++ks) {
        if (ks + 1 < 24) ldw(ks + 1, bn);
        bf16x8 afn = (ks + 1 < 24) ? lda(ks + 1) : af;
#pragma unroll
        for (int i = 0; i < 6; ++i) acc[i] = MFMA_BF16(af, bc[i], acc[i]);
#pragma unroll
        for (int i = 0; i < 6; ++i) bc[i] = bn[i];
        af = afn;
      }
    }

    // ---- epilogue (R20 verbatim, wave<4-gated). acc C/D: col=lane&15,
    // row=quad*4+rr. Stage q/k via qk[32][128], then 2 coalesced 16B
    // write-through stores per thread (tid<256). V direct (frag order). ----
    const int b = m0 >> 11;
    const int v = (m0 & 2047) >> 5;  // 32-key visit within batch

    __syncthreads();     // all waves past their last xs reads
    short* qk = lds;     // overlays xs
    if (wave < 4) {
#pragma unroll
      for (int i = 0; i < 6; ++i) {
        int nt = nh * 6 + i;
        if (nt < 8) {  // q: nt 0-3 -> cols (nt&3)*16+col; k: nt 4-7 -> +64
          int cb = ((nt < 4) ? 0 : 64) + (nt & 3) * 16 + col;
          int r0 = msub * 16 + quad * 4;
#pragma unroll
          for (int r = 0; r < 4; ++r) qk[(r0 + r) * 128 + cb] = f2bf(acc[i][r]);
        }
      }
      if (nh == 1) {
        // V (acc[2..5]): pack straight into MFMA16 A-frag order.
#pragma unroll
        for (int pg = 0; pg < 2; ++pg) {
          unsigned w0 = pkbf(acc[2 + 2 * pg][0], acc[2 + 2 * pg][1]);
          unsigned w1 = pkbf(acc[2 + 2 * pg][2], acc[2 + 2 * pg][3]);
          unsigned w2 = pkbf(acc[3 + 2 * pg][0], acc[3 + 2 * pg][1]);
          unsigned w3 = pkbf(acc[3 + 2 * pg][2], acc[3 + 2 * pg][3]);
          u32x4 pu = {w0, w1, w2, w3};
          st16_sys(vfb + ((size_t)((b * 64 + v) * 4 + msub * 2 + pg)) * 512 + lane * 8,
                   pu);
        }
      }
    }
    __syncthreads();
    if (tid < 256) {
      const int row = tid >> 3, sub = tid & 7;  // 32 rows x 8 col-groups
      short* dst = ((sub < 4) ? qb : kb) + (size_t)(m0 + row) * 64 + (sub & 3) * 16;
      const short* src = &qk[row * 128 + sub * 16];
      st16_sys(dst, *(const u32x4*)(src));
      st16_sys(dst + 8, *(const u32x4*)(src + 8));
    }
  }
  gbar(bar + 64 * 32, bar + 128 * 32 + 32, 512);

  // ============== phase C: flash attention (8-WAY split-K) =================
  {
    short* ksw = &lds[wave * 2304];  // wave-private K tile [32 key][72]

    const int bx = blockIdx.x;
    const int b  = bx & 7;
    // Persistent placement pairs bx with bx+256 on one CU; map qt so each
    // pair is (qt, 63-qt): constant work per CU (perf-only heuristic).
    const int qt = (bx < 256) ? (63 - (bx >> 3)) : ((bx - 256) >> 3);
    const size_t qbase = (size_t)b * 2048 + qt * 32;

    // Q B-frags (pre-scaled): qf[qs][c] -> Q[q=col][h=c*32+quad*8+j]
    bf16x8 qf[2][2];
#pragma unroll
    for (int qs = 0; qs < 2; ++qs)
#pragma unroll
      for (int c = 0; c < 2; ++c)
        qf[qs][c] = *(const bf16x8*)(qb + (qbase + qs * 16 + col) * 64 + c * 32 + quad * 8);

    f32x4 o[2][4];  // O^T accumulators: [qs][ht], row=h_local, col=q
#pragma unroll
    for (int qs = 0; qs < 2; ++qs)
#pragma unroll
      for (int ht = 0; ht < 4; ++ht) o[qs][ht] = (f32x4){0.f, 0.f, 0.f, 0.f};
    float osum[2] = {0.f, 0.f};

    const int nv = qt + 1;  // 32-key visits; wave w takes w, w+8, ...
    const int mycount = (nv > wave) ? ((nv - wave + 7) >> 3) : 0;

    const short* kB = kb + (size_t)b * 2048 * 64;
    const short* vB = vfb + (size_t)b * 64 * 4 * 512;

    bf16x8 kreg[4], vv[4];
    auto issue_k = [&](int v) {  // contiguous 4 KB
      const short* ksrc = kB + (size_t)v * 32 * 64;
#pragma unroll
      for (int it = 0; it < 4; ++it)
        kreg[it] = *(const bf16x8*)(ksrc + lane * 8 + it * 512);
    };
    auto issue_v = [&](int v) {  // frag-order, 1 KB contiguous per load
      const short* vp = vB + (size_t)v * 4 * 512;
#pragma unroll
      for (int g = 0; g < 4; ++g)
        vv[g] = *(const bf16x8*)(vp + g * 512 + lane * 8);
    };
    if (mycount > 0) { issue_k(wave); issue_v(wave); }

    for (int i = 0; i < mycount; ++i) {
      const int v = wave + i * 8;

      // ---- commit prefetched K to private LDS (consumes kreg) ----
#pragma unroll
      for (int it = 0; it < 4; ++it) {
        int e = lane * 8 + it * 512;
        *(bf16x8*)&ksw[(e >> 6) * 72 + (e & 63)] = kreg[it];  // [key][h]
      }
      if (i + 1 < mycount) issue_k(v + 8);  // K prefetch for next visit

      // ---- S^T = K Q^T : A=K[key][h] from LDS, B=Q (regs) ----
      f32x4 st[2][2];  // [qs][t: 16-key tile]
#pragma unroll
      for (int qs = 0; qs < 2; ++qs)
#pragma unroll
        for (int t = 0; t < 2; ++t) st[qs][t] = (f32x4){0.f, 0.f, 0.f, 0.f};
#pragma unroll
      for (int t = 0; t < 2; ++t) {
        const bf16x8 a0 = *(const bf16x8*)&ksw[(t * 16 + col) * 72 + quad * 8];
        const bf16x8 a1 = *(const bf16x8*)&ksw[(t * 16 + col) * 72 + 32 + quad * 8];
#pragma unroll
        for (int qs = 0; qs < 2; ++qs) {
          st[qs][t] = MFMA_BF16(a0, qf[qs][0], st[qs][t]);
          st[qs][t] = MFMA_BF16(a1, qf[qs][1], st[qs][t]);
        }
      }

      // ---- p = exp2(s); causal mask on diagonal visit ----
      const bool diag = (v == qt);  // wave-uniform
      unsigned d[2][2][2];          // packed bf16 P: [qs][t][pair]
#pragma unroll
      for (int qs = 0; qs < 2; ++qs) {
        float part = 0.f;
#pragma unroll
        for (int t = 0; t < 2; ++t) {
          float pr[4];
#pragma unroll
          for (int rr = 0; rr < 4; ++rr) {
            float sv = st[qs][t][rr];
            if (diag && (t * 16 + quad * 4 + rr) > (qs * 16 + col)) sv = -1e30f;
            pr[rr] = __builtin_amdgcn_exp2f(sv);
          }
          d[qs][t][0] = pkbf(pr[0], pr[1]);
          d[qs][t][1] = pkbf(pr[2], pr[3]);
          part += bsum(d[qs][t][0]) + bsum(d[qs][t][1]);
        }
        part += __shfl_xor(part, 16);
        part += __shfl_xor(part, 32);
        osum[qs] += part;
      }

#if HAVE_MFMA16
      // ---- O^T += V^T P^T : V frags straight from vv regs, P from d regs --
#pragma unroll
      for (int t = 0; t < 2; ++t)
#pragma unroll
        for (int pg = 0; pg < 2; ++pg) {
          uint4 u = __builtin_bit_cast(uint4, vv[t * 2 + pg]);
          u32x2 l2 = {u.x, u.y}, h2 = {u.z, u.w};
          bf16x4 vlo = __builtin_bit_cast(bf16x4, l2);  // ht = 2*pg
          bf16x4 vhi = __builtin_bit_cast(bf16x4, h2);  // ht = 2*pg+1
#pragma unroll
          for (int qs = 0; qs < 2; ++qs) {
            u32x2 pd = {d[qs][t][0], d[qs][t][1]};
            bf16x4 pb = __builtin_bit_cast(bf16x4, pd);
            o[qs][2 * pg]     = MFMA16(vlo, pb, o[qs][2 * pg]);
            o[qs][2 * pg + 1] = MFMA16(vhi, pb, o[qs][2 * pg + 1]);
          }
        }
#else
      // ---- fallback: shfl-transpose P (K=32) + shfl-gather V bf16x8 ----
      bf16x8 pbf[2];
#pragma unroll
      for (int qs = 0; qs < 2; ++qs) {
        unsigned dA0 = d[qs][0][0], dB0 = d[qs][0][1];
        unsigned dA1 = d[qs][1][0], dB1 = d[qs][1][1];
        int base = ((quad & 1) << 5) + col;
        unsigned a0  = __shfl(dA0, base),      a1  = __shfl(dA1, base);
        unsigned b0  = __shfl(dB0, base),      b1  = __shfl(dB1, base);
        unsigned a0h = __shfl(dA0, base + 16), a1h = __shfl(dA1, base + 16);
        unsigned b0h = __shfl(dB0, base + 16), b1h = __shfl(dB1, base + 16);
        bool hi = quad >= 2;
        uint4 pu = make_uint4(hi ? a1 : a0, hi ? b1 : b0,
                              hi ? a1h : a0h, hi ? b1h : b0h);
        pbf[qs] = __builtin_bit_cast(bf16x8, pu);
      }
#pragma unroll
      for (int ht = 0; ht < 4; ++ht) {
        int pg = ht >> 1;
        bool odd = ht & 1;
        int L0 = ((quad & 1) * 2) * 16 + col, L1 = L0 + 16;
        uint4 u0 = __builtin_bit_cast(uint4, vv[pg]);
        uint4 u1 = __builtin_bit_cast(uint4, vv[2 + pg]);
        unsigned s0 = odd ? u0.z : u0.x, s1 = odd ? u0.w : u0.y;
        unsigned s2 = odd ? u1.z : u1.x, s3 = odd ? u1.w : u1.y;
        unsigned d0a = __shfl(s0, L0), d1a = __shfl(s1, L0);
        unsigned d2a = __shfl(s0, L1), d3a = __shfl(s1, L1);
        unsigned d0b = __shfl(s2, L0), d1b = __shfl(s3, L0);
        unsigned d2b = __shfl(s2, L1), d3b = __shfl(s3, L1);
        bool t1 = quad >= 2;
        uint4 vu = make_uint4(t1 ? d0b : d0a, t1 ? d1b : d1a,
                              t1 ? d2b : d2a, t1 ? d3b : d3a);
        bf16x8 vf8 = __builtin_bit_cast(bf16x8, vu);
#pragma unroll
        for (int qs = 0; qs < 2; ++qs)
          o[qs][ht] = MFMA_BF16(vf8, pbf[qs], o[qs][ht]);
      }
#endif
      if (i + 1 < mycount) issue_v(v + 8);  // vv free after PV: 1 visit lead
    }

    // ---- 8-way split-K combine: fold 8->4, then 4->1 (pure fp32 add) ----
    __syncthreads();
    float* comb = (float*)lds;  // 4 slots x 64 lanes x 36 floats = 36864 B
    if (wave >= 4) {
      float* p = comb + ((wave - 4) * 64 + lane) * 36;
#pragma unroll
      for (int qs = 0; qs < 2; ++qs)
#pragma unroll
        for (int ht = 0; ht < 4; ++ht)
          *(f32x4*)(p + (qs * 4 + ht) * 4) = o[qs][ht];
      p[32] = osum[0];
      p[33] = osum[1];
    }
    __syncthreads();
    if (wave < 4) {  // wave w absorbs wave w+4
      const float* p = comb + (wave * 64 + lane) * 36;
#pragma unroll
      for (int qs = 0; qs < 2; ++qs)
#pragma unroll
        for (int ht = 0; ht < 4; ++ht)
          o[qs][ht] += *(const f32x4*)(p + (qs * 4 + ht) * 4);
      osum[0] += p[32];
      osum[1] += p[33];
    }
    __syncthreads();
    if (wave >= 1 && wave < 4) {
      float* p = comb + ((wave - 1) * 64 + lane) * 36;
#pragma unroll
      for (int qs = 0; qs < 2; ++qs)
#pragma unroll
        for (int ht = 0; ht < 4; ++ht)
          *(f32x4*)(p + (qs * 4 + ht) * 4) = o[qs][ht];
      p[32] = osum[0];
      p[33] = osum[1];
    }
    __syncthreads();
    if (wave == 0) {
#pragma unroll
      for (int w = 1; w < 4; ++w) {
        const float* p = comb + ((w - 1) * 64 + lane) * 36;
#pragma unroll
        for (int qs = 0; qs < 2; ++qs)
#pragma unroll
          for (int ht = 0; ht < 4; ++ht)
            o[qs][ht] += *(const f32x4*)(p + (qs * 4 + ht) * 4);
        osum[0] += p[32];
        osum[1] += p[33];
      }
      // ---- epilogue: O^T C-layout -> packed float4 stores ----
#pragma unroll
      for (int qs = 0; qs < 2; ++qs) {
        float inv = 1.0f / osum[qs];
#pragma unroll
        for (int ht = 0; ht < 4; ++ht) {
          f32x4 val = o[qs][ht];
#pragma unroll
          for (int rr = 0; rr < 4; ++rr) val[rr] *= inv;
          *(f32x4*)(out + (qbase + qs * 16 + col) * 64 + ht * 16 + quad * 4) = val;
        }
      }
    }
  }
}

// ---------------------------------------------------------------------------
extern "C" void kernel_launch(void* const* d_in, const int* in_sizes, int n_in,
                              void* d_out, int out_size, void* d_ws, size_t ws_size,
                              hipStream_t stream) {
  const float* x  = (const float*)d_in[0];
  const float* Wk = (const float*)d_in[1];
  const float* Wq = (const float*)d_in[2];
  const float* Wv = (const float*)d_in[3];
  float* out = (float*)d_out;

  char* ws = (char*)d_ws;
  // ws layout: wtf (294912 B) | qb 2MB | kb 2MB | vfb 2MB | ... | bar @ 8MB
  // bar: 2 barriers x 64 stripes x 128 B + 2 release words (zeroed below).
  short* wtf = (short*)(ws);
  short* qb  = (short*)(ws + (512 << 10));
  short* kb  = (short*)(ws + (512 << 10) + (2 << 20));
  short* vfb = (short*)(ws + (512 << 10) + (4 << 20));
  unsigned* bar = (unsigned*)(ws + (8 << 20));

  hipMemsetAsync(bar, 0, 20480, stream);  // zero stripes + release words
  fused_kernel<<<512, 512, 0, stream>>>(x, Wk, Wq, Wv, wtf, qb, kb, vfb, bar,
                                        out);
}

// Round 15
// 112.659 us; speedup vs baseline: 1.0667x; 1.0506x over previous
//
#include <hip/hip_runtime.h>

// B=8, T=2048, C=768, HS=64. fp32 in/out; bf16 MFMA internally.
// R23 = R22 with the barrier state moved OUT of the workspace into __device__
// globals + GENERATION-based barrier (no reset ever needed). Why: the
// harness re-poisons the workspace each timed iteration, which forced a
// hipMemsetAsync(bar) dispatch = one extra kernel-launch boundary (~5-8us)
// per iteration. Device globals are never poisoned; monotone generation
// counters (gen = arrivalIdx>>3; 8 arrivals/stripe/invocation, dispatches
// serialize on the stream) make the barrier reusable across graph replays
// with zero initialization. Single dispatch per iteration. All compute
// phases R22-verbatim.

typedef short bf16x8 __attribute__((ext_vector_type(8)));  // 8 bf16 = 4 VGPR
typedef short bf16x4 __attribute__((ext_vector_type(4)));  // 4 bf16 = 2 VGPR
typedef float f32x4  __attribute__((ext_vector_type(4)));
typedef unsigned u32x2 __attribute__((ext_vector_type(2)));
typedef unsigned u32x4 __attribute__((ext_vector_type(4)));

#define MFMA_BF16(a, b, c) __builtin_amdgcn_mfma_f32_16x16x32_bf16((a), (b), (c), 0, 0, 0)

#if __has_builtin(__builtin_amdgcn_mfma_f32_16x16x16bf16_1k)
#define HAVE_MFMA16 1
#define MFMA16(a, b, c) __builtin_amdgcn_mfma_f32_16x16x16bf16_1k((a), (b), (c), 0, 0, 0)
#else
#define HAVE_MFMA16 0
#endif

// scale = C^-0.5 * log2(e), folded into Wq at prep time
#define SCALE_LOG2E 0.05206626f

__device__ __forceinline__ unsigned rbf(float f) {  // RNE bf16 in high 16 bits
  unsigned u = __builtin_bit_cast(unsigned, f);
  return u + 0x7fffu + ((u >> 16) & 1u);
}
__device__ __forceinline__ short f2bf(float f) { return (short)(rbf(f) >> 16); }
__device__ __forceinline__ unsigned pkbf(float a, float b) {  // [lo=a, hi=b]
  return (rbf(a) >> 16) | (rbf(b) & 0xFFFF0000u);
}
__device__ __forceinline__ float bsum(unsigned dw) {  // sum of 2 packed bf16
  float lo = __builtin_bit_cast(float, dw << 16);
  float hi = __builtin_bit_cast(float, dw & 0xFFFF0000u);
  return lo + hi;
}

// System-scope write-through store (gfx950 spellings: sc0 sc1). Data reaches
// the MALL coherence point; no dirty L2 lines -> fence-free grid barrier.
__device__ __forceinline__ void st16_sys(void* p, u32x4 v) {
  asm volatile("global_store_dwordx4 %0, %1, off sc0 sc1" ::"v"(p), "v"(v)
               : "memory");
}

// Barrier state: __device__ globals (zeroed at module load; NEVER in the
// re-poisoned workspace). 64 arrive-stripes x 128B per barrier + 1 release
// word per barrier. Generations are monotone across kernel invocations.
__device__ unsigned g_barA[64 * 32] = {};
__device__ unsigned g_barB[64 * 32] = {};
__device__ unsigned g_relA = 0;
__device__ unsigned g_relB = 0;

// Fence-free two-level GENERATION grid barrier. Prereq: cross-phase data
// stored write-through. Drain own stores -> block barrier -> striped
// device-scope arrive (gen = old>>3: 8 arrivals/stripe/invocation; stream
// ordering guarantees no inter-invocation interleave) -> block 0 aggregates
// to (gen+1)*512 and publishes rel = gen+1 (monotone); others poll the one
// release word with wrap-safe compare. Timeout failsafes keep failure mode =
// visible wrong answer, never a hang.
__device__ __forceinline__ void gbar(unsigned* ctr, unsigned* rel) {
  asm volatile("s_waitcnt vmcnt(0)" ::: "memory");
  __syncthreads();
  if (threadIdx.x == 0) {
    unsigned old = atomicAdd(&ctr[(blockIdx.x & 63) * 32], 1u);
    unsigned gen = old >> 3;  // 8 blocks share each stripe per invocation
    long long t0 = (long long)__builtin_amdgcn_s_memtime();
    if (blockIdx.x == 0) {
      unsigned need = (gen + 1) * 512;
      for (;;) {
        unsigned s = 0;
#pragma unroll
        for (int i = 0; i < 64; ++i)
          s += __hip_atomic_load(&ctr[i * 32], __ATOMIC_RELAXED,
                                 __HIP_MEMORY_SCOPE_AGENT);
        if (s >= need) break;
        __builtin_amdgcn_s_sleep(2);
        if ((long long)__builtin_amdgcn_s_memtime() - t0 > (1LL << 28)) break;
      }
      __hip_atomic_store(rel, gen + 1, __ATOMIC_RELAXED,
                         __HIP_MEMORY_SCOPE_AGENT);
    } else {
      while ((int)(__hip_atomic_load(rel, __ATOMIC_RELAXED,
                                     __HIP_MEMORY_SCOPE_AGENT) -
                   (gen + 1)) < 0) {
        __builtin_amdgcn_s_sleep(16);
        if ((long long)__builtin_amdgcn_s_memtime() - t0 > (1LL << 28)) break;
      }
    }
    asm volatile("" ::: "memory");  // keep later loads below the poll
  }
  __syncthreads();
}

// ---------------------------------------------------------------------------
// Fused kernel. 512 blocks x 512 threads, plain launch (ONLY dispatch).
// LDS union (49664 B = 24832 shorts):
//   B: xs[32][776] bf16 x-tile (staged once by all 8 waves, read by 4)
//   B epilogue: qk[32][128] = shorts [0,4096)  (xs dead)
//   C: ksw 8 waves x 2304 shorts = [0,18432) ; combine 4 slots (36864 B)
// Co-residency: __launch_bounds__(512,4) + 49.7 KB LDS (2x = 99 KB < 160 KB)
// -> 2 blocks/CU x 256 CU = 512 = grid.
// ---------------------------------------------------------------------------
__global__ __launch_bounds__(512, 4) void fused_kernel(
    const float* __restrict__ x, const float* __restrict__ Wk,
    const float* __restrict__ Wq, const float* __restrict__ Wv,
    short* __restrict__ wtf, short* __restrict__ qb, short* __restrict__ kb,
    short* __restrict__ vfb, float* __restrict__ out) {
  __shared__ __attribute__((aligned(16))) short lds[24832];

  const int tid  = threadIdx.x;
  const int wave = tid >> 6;
  const int lane = tid & 63;
  const int quad = lane >> 4;
  const int col  = lane & 15;

  // ============== phase A: prep wtf (B-fragment-order weights) =============
  // wtf[ks 0..23][nt 0..11][lane 0..63][8 bf16]; nt 0-3 Wq (pre-scaled),
  // 4-7 Wk, 8-11 Wv.
  {
    int gid = blockIdx.x * 512 + tid;
    if (gid < 24 * 12 * 64) {
      int ks   = gid / 768;
      int rem  = gid - ks * 768;
      int nt   = rem >> 6;
      int pl   = rem & 63;
      int pq = pl >> 4, pc = pl & 15;
      const float* W = (nt < 4) ? Wq : (nt < 8) ? Wk : Wv;
      float s = (nt < 4) ? SCALE_LOG2E : 1.0f;
      int h  = (nt & 3) * 16 + pc;
      int k0 = ks * 32 + pq * 8;
      bf16x8 v;
#pragma unroll
      for (int j = 0; j < 8; ++j) v[j] = f2bf(W[(k0 + j) * 64 + h] * s);
      st16_sys(wtf + (size_t)gid * 8, __builtin_bit_cast(u32x4, v));
    }
  }
  gbar(g_barA, &g_relA);

  // ============== phase B: projections (x-in-LDS, zero-barrier loop) =======
  {
    short* xs = lds;  // [32][776] bf16, row stride 776 (rows 16B-aligned)

    const int msub = wave >> 1;   // valid for wave<4 (MFMA waves)
    const int nh   = wave & 1;
    const int m0   = blockIdx.x * 32;

    // ---- stage x tile once (ALL 8 waves): 32 x 768 fp32 -> bf16 ----
#pragma unroll 4
    for (int it = 0; it < 12; ++it) {
      int f   = tid + it * 512;        // [0, 6144)
      int row = f / 192, c4 = f - row * 192;
      float4 xv = *(const float4*)(x + (size_t)(m0 + row) * 768 + c4 * 4);
      unsigned lo = pkbf(xv.x, xv.y);
      unsigned hi = pkbf(xv.z, xv.w);
      *(uint2*)&xs[row * 776 + c4 * 4] = make_uint2(lo, hi);
    }
    __syncthreads();

    // ---- MFMA loop (waves 0-3 only; barrier-free): B-frags straight from
    // wtf (frag order, L2-resident), double-buffered one k-step ahead. ----
    f32x4 acc[6];
#pragma unroll
    for (int i = 0; i < 6; ++i) acc[i] = (f32x4){0.f, 0.f, 0.f, 0.f};

    if (wave < 4) {
      auto ldw = [&](int ks, bf16x8* dst) {
        const short* p = wtf + (size_t)ks * 6144 + ((nh * 6) * 64 + lane) * 8;
#pragma unroll
        for (int i = 0; i < 6; ++i) dst[i] = *(const bf16x8*)(p + i * 512);
      };
      auto lda = [&](int ks) {
        return *(const bf16x8*)&xs[(msub * 16 + col) * 776 + ks * 32 + quad * 8];
      };

      bf16x8 bc[6], bn[6];
      ldw(0, bc);
      bf16x8 af = lda(0);
      for (int ks = 0; ks < 24; ++ks) {
        if (ks + 1 < 24) ldw(ks + 1, bn);
        bf16x8 afn = (ks + 1 < 24) ? lda(ks + 1) : af;
#pragma unroll
        for (int i = 0; i < 6; ++i) acc[i] = MFMA_BF16(af, bc[i], acc[i]);
#pragma unroll
        for (int i = 0; i < 6; ++i) bc[i] = bn[i];
        af = afn;
      }
    }

    // ---- epilogue (R20 verbatim, wave<4-gated). acc C/D: col=lane&15,
    // row=quad*4+rr. Stage q/k via qk[32][128], then 2 coalesced 16B
    // write-through stores per thread (tid<256). V direct (frag order). ----
    const int b = m0 >> 11;
    const int v = (m0 & 2047) >> 5;  // 32-key visit within batch

    __syncthreads();     // all waves past their last xs reads
    short* qk = lds;     // overlays xs
    if (wave < 4) {
#pragma unroll
      for (int i = 0; i < 6; ++i) {
        int nt = nh * 6 + i;
        if (nt < 8) {  // q: nt 0-3 -> cols (nt&3)*16+col; k: nt 4-7 -> +64
          int cb = ((nt < 4) ? 0 : 64) + (nt & 3) * 16 + col;
          int r0 = msub * 16 + quad * 4;
#pragma unroll
          for (int r = 0; r < 4; ++r) qk[(r0 + r) * 128 + cb] = f2bf(acc[i][r]);
        }
      }
      if (nh == 1) {
        // V (acc[2..5]): pack straight into MFMA16 A-frag order.
#pragma unroll
        for (int pg = 0; pg < 2; ++pg) {
          unsigned w0 = pkbf(acc[2 + 2 * pg][0], acc[2 + 2 * pg][1]);
          unsigned w1 = pkbf(acc[2 + 2 * pg][2], acc[2 + 2 * pg][3]);
          unsigned w2 = pkbf(acc[3 + 2 * pg][0], acc[3 + 2 * pg][1]);
          unsigned w3 = pkbf(acc[3 + 2 * pg][2], acc[3 + 2 * pg][3]);
          u32x4 pu = {w0, w1, w2, w3};
          st16_sys(vfb + ((size_t)((b * 64 + v) * 4 + msub * 2 + pg)) * 512 + lane * 8,
                   pu);
        }
      }
    }
    __syncthreads();
    if (tid < 256) {
      const int row = tid >> 3, sub = tid & 7;  // 32 rows x 8 col-groups
      short* dst = ((sub < 4) ? qb : kb) + (size_t)(m0 + row) * 64 + (sub & 3) * 16;
      const short* src = &qk[row * 128 + sub * 16];
      st16_sys(dst, *(const u32x4*)(src));
      st16_sys(dst + 8, *(const u32x4*)(src + 8));
    }
  }
  gbar(g_barB, &g_relB);

  // ============== phase C: flash attention (8-WAY split-K) =================
  {
    short* ksw = &lds[wave * 2304];  // wave-private K tile [32 key][72]

    const int bx = blockIdx.x;
    const int b  = bx & 7;
    // Persistent placement pairs bx with bx+256 on one CU; map qt so each
    // pair is (qt, 63-qt): constant work per CU (perf-only heuristic).
    const int qt = (bx < 256) ? (63 - (bx >> 3)) : ((bx - 256) >> 3);
    const size_t qbase = (size_t)b * 2048 + qt * 32;

    // Q B-frags (pre-scaled): qf[qs][c] -> Q[q=col][h=c*32+quad*8+j]
    bf16x8 qf[2][2];
#pragma unroll
    for (int qs = 0; qs < 2; ++qs)
#pragma unroll
      for (int c = 0; c < 2; ++c)
        qf[qs][c] = *(const bf16x8*)(qb + (qbase + qs * 16 + col) * 64 + c * 32 + quad * 8);

    f32x4 o[2][4];  // O^T accumulators: [qs][ht], row=h_local, col=q
#pragma unroll
    for (int qs = 0; qs < 2; ++qs)
#pragma unroll
      for (int ht = 0; ht < 4; ++ht) o[qs][ht] = (f32x4){0.f, 0.f, 0.f, 0.f};
    float osum[2] = {0.f, 0.f};

    const int nv = qt + 1;  // 32-key visits; wave w takes w, w+8, ...
    const int mycount = (nv > wave) ? ((nv - wave + 7) >> 3) : 0;

    const short* kB = kb + (size_t)b * 2048 * 64;
    const short* vB = vfb + (size_t)b * 64 * 4 * 512;

    bf16x8 kreg[4], vv[4];
    auto issue_k = [&](int v) {  // contiguous 4 KB
      const short* ksrc = kB + (size_t)v * 32 * 64;
#pragma unroll
      for (int it = 0; it < 4; ++it)
        kreg[it] = *(const bf16x8*)(ksrc + lane * 8 + it * 512);
    };
    auto issue_v = [&](int v) {  // frag-order, 1 KB contiguous per load
      const short* vp = vB + (size_t)v * 4 * 512;
#pragma unroll
      for (int g = 0; g < 4; ++g)
        vv[g] = *(const bf16x8*)(vp + g * 512 + lane * 8);
    };
    if (mycount > 0) { issue_k(wave); issue_v(wave); }

    for (int i = 0; i < mycount; ++i) {
      const int v = wave + i * 8;

      // ---- commit prefetched K to private LDS (consumes kreg) ----
#pragma unroll
      for (int it = 0; it < 4; ++it) {
        int e = lane * 8 + it * 512;
        *(bf16x8*)&ksw[(e >> 6) * 72 + (e & 63)] = kreg[it];  // [key][h]
      }
      if (i + 1 < mycount) issue_k(v + 8);  // K prefetch for next visit

      // ---- S^T = K Q^T : A=K[key][h] from LDS, B=Q (regs) ----
      f32x4 st[2][2];  // [qs][t: 16-key tile]
#pragma unroll
      for (int qs = 0; qs < 2; ++qs)
#pragma unroll
        for (int t = 0; t < 2; ++t) st[qs][t] = (f32x4){0.f, 0.f, 0.f, 0.f};
#pragma unroll
      for (int t = 0; t < 2; ++t) {
        const bf16x8 a0 = *(const bf16x8*)&ksw[(t * 16 + col) * 72 + quad * 8];
        const bf16x8 a1 = *(const bf16x8*)&ksw[(t * 16 + col) * 72 + 32 + quad * 8];
#pragma unroll
        for (int qs = 0; qs < 2; ++qs) {
          st[qs][t] = MFMA_BF16(a0, qf[qs][0], st[qs][t]);
          st[qs][t] = MFMA_BF16(a1, qf[qs][1], st[qs][t]);
        }
      }

      // ---- p = exp2(s); causal mask on diagonal visit ----
      const bool diag = (v == qt);  // wave-uniform
      unsigned d[2][2][2];          // packed bf16 P: [qs][t][pair]
#pragma unroll
      for (int qs = 0; qs < 2; ++qs) {
        float part = 0.f;
#pragma unroll
        for (int t = 0; t < 2; ++t) {
          float pr[4];
#pragma unroll
          for (int rr = 0; rr < 4; ++rr) {
            float sv = st[qs][t][rr];
            if (diag && (t * 16 + quad * 4 + rr) > (qs * 16 + col)) sv = -1e30f;
            pr[rr] = __builtin_amdgcn_exp2f(sv);
          }
          d[qs][t][0] = pkbf(pr[0], pr[1]);
          d[qs][t][1] = pkbf(pr[2], pr[3]);
          part += bsum(d[qs][t][0]) + bsum(d[qs][t][1]);
        }
        part += __shfl_xor(part, 16);
        part += __shfl_xor(part, 32);
        osum[qs] += part;
      }

#if HAVE_MFMA16
      // ---- O^T += V^T P^T : V frags straight from vv regs, P from d regs --
#pragma unroll
      for (int t = 0; t < 2; ++t)
#pragma unroll
        for (int pg = 0; pg < 2; ++pg) {
          uint4 u = __builtin_bit_cast(uint4, vv[t * 2 + pg]);
          u32x2 l2 = {u.x, u.y}, h2 = {u.z, u.w};
          bf16x4 vlo = __builtin_bit_cast(bf16x4, l2);  // ht = 2*pg
          bf16x4 vhi = __builtin_bit_cast(bf16x4, h2);  // ht = 2*pg+1
#pragma unroll
          for (int qs = 0; qs < 2; ++qs) {
            u32x2 pd = {d[qs][t][0], d[qs][t][1]};
            bf16x4 pb = __builtin_bit_cast(bf16x4, pd);
            o[qs][2 * pg]     = MFMA16(vlo, pb, o[qs][2 * pg]);
            o[qs][2 * pg + 1] = MFMA16(vhi, pb, o[qs][2 * pg + 1]);
          }
        }
#else
      // ---- fallback: shfl-transpose P (K=32) + shfl-gather V bf16x8 ----
      bf16x8 pbf[2];
#pragma unroll
      for (int qs = 0; qs < 2; ++qs) {
        unsigned dA0 = d[qs][0][0], dB0 = d[qs][0][1];
        unsigned dA1 = d[qs][1][0], dB1 = d[qs][1][1];
        int base = ((quad & 1) << 5) + col;
        unsigned a0  = __shfl(dA0, base),      a1  = __shfl(dA1, base);
        unsigned b0  = __shfl(dB0, base),      b1  = __shfl(dB1, base);
        unsigned a0h = __shfl(dA0, base + 16), a1h = __shfl(dA1, base + 16);
        unsigned b0h = __shfl(dB0, base + 16), b1h = __shfl(dB1, base + 16);
        bool hi = quad >= 2;
        uint4 pu = make_uint4(hi ? a1 : a0, hi ? b1 : b0,
                              hi ? a1h : a0h, hi ? b1h : b0h);
        pbf[qs] = __builtin_bit_cast(bf16x8, pu);
      }
#pragma unroll
      for (int ht = 0; ht < 4; ++ht) {
        int pg = ht >> 1;
        bool odd = ht & 1;
        int L0 = ((quad & 1) * 2) * 16 + col, L1 = L0 + 16;
        uint4 u0 = __builtin_bit_cast(uint4, vv[pg]);
        uint4 u1 = __builtin_bit_cast(uint4, vv[2 + pg]);
        unsigned s0 = odd ? u0.z : u0.x, s1 = odd ? u0.w : u0.y;
        unsigned s2 = odd ? u1.z : u1.x, s3 = odd ? u1.w : u1.y;
        unsigned d0a = __shfl(s0, L0), d1a = __shfl(s1, L0);
        unsigned d2a = __shfl(s0, L1), d3a = __shfl(s1, L1);
        unsigned d0b = __shfl(s2, L0), d1b = __shfl(s3, L0);
        unsigned d2b = __shfl(s2, L1), d3b = __shfl(s3, L1);
        bool t1 = quad >= 2;
        uint4 vu = make_uint4(t1 ? d0b : d0a, t1 ? d1b : d1a,
                              t1 ? d2b : d2a, t1 ? d3b : d3a);
        bf16x8 vf8 = __builtin_bit_cast(bf16x8, vu);
#pragma unroll
        for (int qs = 0; qs < 2; ++qs)
          o[qs][ht] = MFMA_BF16(vf8, pbf[qs], o[qs][ht]);
      }
#endif
      if (i + 1 < mycount) issue_v(v + 8);  // vv free after PV: 1 visit lead
    }

    // ---- 8-way split-K combine: fold 8->4, then 4->1 (pure fp32 add) ----
    __syncthreads();
    float* comb = (float*)lds;  // 4 slots x 64 lanes x 36 floats = 36864 B
    if (wave >= 4) {
      float* p = comb + ((wave - 4) * 64 + lane) * 36;
#pragma unroll
      for (int qs = 0; qs < 2; ++qs)
#pragma unroll
        for (int ht = 0; ht < 4; ++ht)
          *(f32x4*)(p + (qs * 4 + ht) * 4) = o[qs][ht];
      p[32] = osum[0];
      p[33] = osum[1];
    }
    __syncthreads();
    if (wave < 4) {  // wave w absorbs wave w+4
      const float* p = comb + (wave * 64 + lane) * 36;
#pragma unroll
      for (int qs = 0; qs < 2; ++qs)
#pragma unroll
        for (int ht = 0; ht < 4; ++ht)
          o[qs][ht] += *(const f32x4*)(p + (qs * 4 + ht) * 4);
      osum[0] += p[32];
      osum[1] += p[33];
    }
    __syncthreads();
    if (wave >= 1 && wave < 4) {
      float* p = comb + ((wave - 1) * 64 + lane) * 36;
#pragma unroll
      for (int qs = 0; qs < 2; ++qs)
#pragma unroll
        for (int ht = 0; ht < 4; ++ht)
          *(f32x4*)(p + (qs * 4 + ht) * 4) = o[qs][ht];
      p[32] = osum[0];
      p[33] = osum[1];
    }
    __syncthreads();
    if (wave == 0) {
#pragma unroll
      for (int w = 1; w < 4; ++w) {
        const float* p = comb + ((w - 1) * 64 + lane) * 36;
#pragma unroll
        for (int qs = 0; qs < 2; ++qs)
#pragma unroll
          for (int ht = 0; ht < 4; ++ht)
            o[qs][ht] += *(const f32x4*)(p + (qs * 4 + ht) * 4);
        osum[0] += p[32];
        osum[1] += p[33];
      }
      // ---- epilogue: O^T C-layout -> packed float4 stores ----
#pragma unroll
      for (int qs = 0; qs < 2; ++qs) {
        float inv = 1.0f / osum[qs];
#pragma unroll
        for (int ht = 0; ht < 4; ++ht) {
          f32x4 val = o[qs][ht];
#pragma unroll
          for (int rr = 0; rr < 4; ++rr) val[rr] *= inv;
          *(f32x4*)(out + (qbase + qs * 16 + col) * 64 + ht * 16 + quad * 4) = val;
        }
      }
    }
  }
}

// ---------------------------------------------------------------------------
extern "C" void kernel_launch(void* const* d_in, const int* in_sizes, int n_in,
                              void* d_out, int out_size, void* d_ws, size_t ws_size,
                              hipStream_t stream) {
  const float* x  = (const float*)d_in[0];
  const float* Wk = (const float*)d_in[1];
  const float* Wq = (const float*)d_in[2];
  const float* Wv = (const float*)d_in[3];
  float* out = (float*)d_out;

  char* ws = (char*)d_ws;
  // ws layout: wtf (294912 B) | qb 2MB | kb 2MB | vfb 2MB
  // (barrier state lives in __device__ globals -- no memset dispatch)
  short* wtf = (short*)(ws);
  short* qb  = (short*)(ws + (512 << 10));
  short* kb  = (short*)(ws + (512 << 10) + (2 << 20));
  short* vfb = (short*)(ws + (512 << 10) + (4 << 20));

  fused_kernel<<<512, 512, 0, stream>>>(x, Wk, Wq, Wv, wtf, qb, kb, vfb, out);
}

// Round 16
// 111.970 us; speedup vs baseline: 1.0733x; 1.0061x over previous
//
#include <hip/hip_runtime.h>

// B=8, T=2048, C=768, HS=64. fp32 in/out; bf16 MFMA internally.
// R24 = R23 with sync SCOPED PER BATCH-GROUP. The fused dispatch sat at
// ~44-46us across three internal redesigns while bodies model ~10-15us: the
// residual is GLOBAL barrier skew (2x wait-for-slowest-of-512, including the
// launch ramp). Dataflow is per-batch: group g = bx>>6 (64 blocks) produces
// batch g's q/k/v in phase B and consumes ONLY batch g in phase C. wtf is
// replicated per group (8 x 288KB) to kill the one cross-group dependency.
// => 8 independent 64-block pipelines, two GROUP-LOCAL generation barriers
// each (8 stripes x 8 arrivals), no global sync at all. Phase C balance:
// qt = (b<4) ? l : 63-l (bijective per group; CU pair (b,l)/(b+4,l) sums to
// constant 65 visits). All compute bodies R23-verbatim.

typedef short bf16x8 __attribute__((ext_vector_type(8)));  // 8 bf16 = 4 VGPR
typedef short bf16x4 __attribute__((ext_vector_type(4)));  // 4 bf16 = 2 VGPR
typedef float f32x4  __attribute__((ext_vector_type(4)));
typedef unsigned u32x2 __attribute__((ext_vector_type(2)));
typedef unsigned u32x4 __attribute__((ext_vector_type(4)));

#define MFMA_BF16(a, b, c) __builtin_amdgcn_mfma_f32_16x16x32_bf16((a), (b), (c), 0, 0, 0)

#if __has_builtin(__builtin_amdgcn_mfma_f32_16x16x16bf16_1k)
#define HAVE_MFMA16 1
#define MFMA16(a, b, c) __builtin_amdgcn_mfma_f32_16x16x16bf16_1k((a), (b), (c), 0, 0, 0)
#else
#define HAVE_MFMA16 0
#endif

// scale = C^-0.5 * log2(e), folded into Wq at prep time
#define SCALE_LOG2E 0.05206626f

__device__ __forceinline__ unsigned rbf(float f) {  // RNE bf16 in high 16 bits
  unsigned u = __builtin_bit_cast(unsigned, f);
  return u + 0x7fffu + ((u >> 16) & 1u);
}
__device__ __forceinline__ short f2bf(float f) { return (short)(rbf(f) >> 16); }
__device__ __forceinline__ unsigned pkbf(float a, float b) {  // [lo=a, hi=b]
  return (rbf(a) >> 16) | (rbf(b) & 0xFFFF0000u);
}
__device__ __forceinline__ float bsum(unsigned dw) {  // sum of 2 packed bf16
  float lo = __builtin_bit_cast(float, dw << 16);
  float hi = __builtin_bit_cast(float, dw & 0xFFFF0000u);
  return lo + hi;
}

// System-scope write-through store (gfx950 spellings: sc0 sc1). Data reaches
// the MALL coherence point; no dirty L2 lines -> fence-free barriers.
__device__ __forceinline__ void st16_sys(void* p, u32x4 v) {
  asm volatile("global_store_dwordx4 %0, %1, off sc0 sc1" ::"v"(p), "v"(v)
               : "memory");
}

// Barrier state: __device__ globals (zeroed at module load; never poisoned).
// Per group: 8 arrive-stripes x 128B + 1 release word. Generations are
// monotone across kernel invocations (no reset dispatch needed).
__device__ unsigned g_barA[8][8 * 32] = {};
__device__ unsigned g_barB[8][8 * 32] = {};
__device__ unsigned g_relA[8] = {};
__device__ unsigned g_relB[8] = {};

// Fence-free two-level GENERATION barrier, GROUP-SCOPED (64 blocks).
// Drain own write-through stores -> block barrier -> striped device-scope
// arrive (gen = old>>3: 8 arrivals/stripe/invocation; stream ordering
// prevents inter-invocation interleave) -> group-local block 0 aggregates to
// (gen+1)*64 and publishes rel = gen+1 (monotone); others poll the single
// release word with wrap-safe compare. Timeout failsafes keep failure mode =
// visible wrong answer, never a hang.
__device__ __forceinline__ void gbar_g(unsigned* ctr, unsigned* rel, int l) {
  asm volatile("s_waitcnt vmcnt(0)" ::: "memory");
  __syncthreads();
  if (threadIdx.x == 0) {
    unsigned old = atomicAdd(&ctr[(l & 7) * 32], 1u);
    unsigned gen = old >> 3;  // 8 blocks share each stripe per invocation
    long long t0 = (long long)__builtin_amdgcn_s_memtime();
    if (l == 0) {
      unsigned need = (gen + 1) * 64;
      for (;;) {
        unsigned s = 0;
#pragma unroll
        for (int i = 0; i < 8; ++i)
          s += __hip_atomic_load(&ctr[i * 32], __ATOMIC_RELAXED,
                                 __HIP_MEMORY_SCOPE_AGENT);
        if (s >= need) break;
        __builtin_amdgcn_s_sleep(2);
        if ((long long)__builtin_amdgcn_s_memtime() - t0 > (1LL << 28)) break;
      }
      __hip_atomic_store(rel, gen + 1, __ATOMIC_RELAXED,
                         __HIP_MEMORY_SCOPE_AGENT);
    } else {
      while ((int)(__hip_atomic_load(rel, __ATOMIC_RELAXED,
                                     __HIP_MEMORY_SCOPE_AGENT) -
                   (gen + 1)) < 0) {
        __builtin_amdgcn_s_sleep(8);
        if ((long long)__builtin_amdgcn_s_memtime() - t0 > (1LL << 28)) break;
      }
    }
    asm volatile("" ::: "memory");  // keep later loads below the poll
  }
  __syncthreads();
}

// ---------------------------------------------------------------------------
// Fused kernel. 512 blocks x 512 threads, plain launch (ONLY dispatch).
// LDS union (49664 B = 24832 shorts):
//   B: xs[32][776] bf16 x-tile (staged once by all 8 waves, read by 4)
//   B epilogue: qk[32][128] = shorts [0,4096)  (xs dead)
//   C: ksw 8 waves x 2304 shorts = [0,18432) ; combine 4 slots (36864 B)
// Co-residency: __launch_bounds__(512,4) + 49.7 KB LDS (2x = 99 KB < 160 KB)
// -> 2 blocks/CU x 256 CU = 512 = grid.
// ---------------------------------------------------------------------------
__global__ __launch_bounds__(512, 4) void fused_kernel(
    const float* __restrict__ x, const float* __restrict__ Wk,
    const float* __restrict__ Wq, const float* __restrict__ Wv,
    short* __restrict__ wtf, short* __restrict__ qb, short* __restrict__ kb,
    short* __restrict__ vfb, float* __restrict__ out) {
  __shared__ __attribute__((aligned(16))) short lds[24832];

  const int tid  = threadIdx.x;
  const int wave = tid >> 6;
  const int lane = tid & 63;
  const int quad = lane >> 4;
  const int col  = lane & 15;
  const int g    = blockIdx.x >> 6;   // batch group (8 x 64 blocks)
  const int l    = blockIdx.x & 63;   // block id within group
  short* wtfg    = wtf + (size_t)g * 147456;  // group-private wtf copy

  // ============== phase A: prep wtf copy for THIS group ====================
  // wtfg[ks 0..23][nt 0..11][lane 0..63][8 bf16]; nt 0-3 Wq (pre-scaled),
  // 4-7 Wk, 8-11 Wv. 36 of 64 blocks active (18432 lanes of work).
  {
    int gid = l * 512 + tid;
    if (gid < 24 * 12 * 64) {
      int ks   = gid / 768;
      int rem  = gid - ks * 768;
      int nt   = rem >> 6;
      int pl   = rem & 63;
      int pq = pl >> 4, pc = pl & 15;
      const float* W = (nt < 4) ? Wq : (nt < 8) ? Wk : Wv;
      float s = (nt < 4) ? SCALE_LOG2E : 1.0f;
      int h  = (nt & 3) * 16 + pc;
      int k0 = ks * 32 + pq * 8;
      bf16x8 v;
#pragma unroll
      for (int j = 0; j < 8; ++j) v[j] = f2bf(W[(k0 + j) * 64 + h] * s);
      st16_sys(wtfg + (size_t)gid * 8, __builtin_bit_cast(u32x4, v));
    }
  }
  gbar_g(g_barA[g], &g_relA[g], l);

  // ============== phase B: projections (x-in-LDS, zero-barrier loop) =======
  {
    short* xs = lds;  // [32][776] bf16, row stride 776 (rows 16B-aligned)

    const int msub = wave >> 1;   // valid for wave<4 (MFMA waves)
    const int nh   = wave & 1;
    const int m0   = blockIdx.x * 32;   // batch = m0>>11 = g  (consistent)

    // ---- stage x tile once (ALL 8 waves): 32 x 768 fp32 -> bf16 ----
#pragma unroll 4
    for (int it = 0; it < 12; ++it) {
      int f   = tid + it * 512;        // [0, 6144)
      int row = f / 192, c4 = f - row * 192;
      float4 xv = *(const float4*)(x + (size_t)(m0 + row) * 768 + c4 * 4);
      unsigned lo = pkbf(xv.x, xv.y);
      unsigned hi = pkbf(xv.z, xv.w);
      *(uint2*)&xs[row * 776 + c4 * 4] = make_uint2(lo, hi);
    }
    __syncthreads();

    // ---- MFMA loop (waves 0-3 only; barrier-free): B-frags straight from
    // wtfg (frag order, L2-resident), double-buffered one k-step ahead. ----
    f32x4 acc[6];
#pragma unroll
    for (int i = 0; i < 6; ++i) acc[i] = (f32x4){0.f, 0.f, 0.f, 0.f};

    if (wave < 4) {
      auto ldw = [&](int ks, bf16x8* dst) {
        const short* p = wtfg + (size_t)ks * 6144 + ((nh * 6) * 64 + lane) * 8;
#pragma unroll
        for (int i = 0; i < 6; ++i) dst[i] = *(const bf16x8*)(p + i * 512);
      };
      auto lda = [&](int ks) {
        return *(const bf16x8*)&xs[(msub * 16 + col) * 776 + ks * 32 + quad * 8];
      };

      bf16x8 bc[6], bn[6];
      ldw(0, bc);
      bf16x8 af = lda(0);
      for (int ks = 0; ks < 24; ++ks) {
        if (ks + 1 < 24) ldw(ks + 1, bn);
        bf16x8 afn = (ks + 1 < 24) ? lda(ks + 1) : af;
#pragma unroll
        for (int i = 0; i < 6; ++i) acc[i] = MFMA_BF16(af, bc[i], acc[i]);
#pragma unroll
        for (int i = 0; i < 6; ++i) bc[i] = bn[i];
        af = afn;
      }
    }

    // ---- epilogue (R20 verbatim, wave<4-gated). acc C/D: col=lane&15,
    // row=quad*4+rr. Stage q/k via qk[32][128], then 2 coalesced 16B
    // write-through stores per thread (tid<256). V direct (frag order). ----
    const int b = m0 >> 11;
    const int v = (m0 & 2047) >> 5;  // 32-key visit within batch

    __syncthreads();     // all waves past their last xs reads
    short* qk = lds;     // overlays xs
    if (wave < 4) {
#pragma unroll
      for (int i = 0; i < 6; ++i) {
        int nt = nh * 6 + i;
        if (nt < 8) {  // q: nt 0-3 -> cols (nt&3)*16+col; k: nt 4-7 -> +64
          int cb = ((nt < 4) ? 0 : 64) + (nt & 3) * 16 + col;
          int r0 = msub * 16 + quad * 4;
#pragma unroll
          for (int r = 0; r < 4; ++r) qk[(r0 + r) * 128 + cb] = f2bf(acc[i][r]);
        }
      }
      if (nh == 1) {
        // V (acc[2..5]): pack straight into MFMA16 A-frag order.
#pragma unroll
        for (int pg = 0; pg < 2; ++pg) {
          unsigned w0 = pkbf(acc[2 + 2 * pg][0], acc[2 + 2 * pg][1]);
          unsigned w1 = pkbf(acc[2 + 2 * pg][2], acc[2 + 2 * pg][3]);
          unsigned w2 = pkbf(acc[3 + 2 * pg][0], acc[3 + 2 * pg][1]);
          unsigned w3 = pkbf(acc[3 + 2 * pg][2], acc[3 + 2 * pg][3]);
          u32x4 pu = {w0, w1, w2, w3};
          st16_sys(vfb + ((size_t)((b * 64 + v) * 4 + msub * 2 + pg)) * 512 + lane * 8,
                   pu);
        }
      }
    }
    __syncthreads();
    if (tid < 256) {
      const int row = tid >> 3, sub = tid & 7;  // 32 rows x 8 col-groups
      short* dst = ((sub < 4) ? qb : kb) + (size_t)(m0 + row) * 64 + (sub & 3) * 16;
      const short* src = &qk[row * 128 + sub * 16];
      st16_sys(dst, *(const u32x4*)(src));
      st16_sys(dst + 8, *(const u32x4*)(src + 8));
    }
  }
  gbar_g(g_barB[g], &g_relB[g], l);

  // ============== phase C: flash attention (8-WAY split-K, group-local) ====
  {
    short* ksw = &lds[wave * 2304];  // wave-private K tile [32 key][72]

    const int b  = g;                       // batch = own group
    // qt bijective within group; CU pair (b,l)/(b+4,l) sums to 65 visits.
    const int qt = (b < 4) ? l : (63 - l);
    const size_t qbase = (size_t)b * 2048 + qt * 32;

    // Q B-frags (pre-scaled): qf[qs][c] -> Q[q=col][h=c*32+quad*8+j]
    bf16x8 qf[2][2];
#pragma unroll
    for (int qs = 0; qs < 2; ++qs)
#pragma unroll
      for (int c = 0; c < 2; ++c)
        qf[qs][c] = *(const bf16x8*)(qb + (qbase + qs * 16 + col) * 64 + c * 32 + quad * 8);

    f32x4 o[2][4];  // O^T accumulators: [qs][ht], row=h_local, col=q
#pragma unroll
    for (int qs = 0; qs < 2; ++qs)
#pragma unroll
      for (int ht = 0; ht < 4; ++ht) o[qs][ht] = (f32x4){0.f, 0.f, 0.f, 0.f};
    float osum[2] = {0.f, 0.f};

    const int nv = qt + 1;  // 32-key visits; wave w takes w, w+8, ...
    const int mycount = (nv > wave) ? ((nv - wave + 7) >> 3) : 0;

    const short* kB = kb + (size_t)b * 2048 * 64;
    const short* vB = vfb + (size_t)b * 64 * 4 * 512;

    bf16x8 kreg[4], vv[4];
    auto issue_k = [&](int v) {  // contiguous 4 KB
      const short* ksrc = kB + (size_t)v * 32 * 64;
#pragma unroll
      for (int it = 0; it < 4; ++it)
        kreg[it] = *(const bf16x8*)(ksrc + lane * 8 + it * 512);
    };
    auto issue_v = [&](int v) {  // frag-order, 1 KB contiguous per load
      const short* vp = vB + (size_t)v * 4 * 512;
#pragma unroll
      for (int g2 = 0; g2 < 4; ++g2)
        vv[g2] = *(const bf16x8*)(vp + g2 * 512 + lane * 8);
    };
    if (mycount > 0) { issue_k(wave); issue_v(wave); }

    for (int i = 0; i < mycount; ++i) {
      const int v = wave + i * 8;

      // ---- commit prefetched K to private LDS (consumes kreg) ----
#pragma unroll
      for (int it = 0; it < 4; ++it) {
        int e = lane * 8 + it * 512;
        *(bf16x8*)&ksw[(e >> 6) * 72 + (e & 63)] = kreg[it];  // [key][h]
      }
      if (i + 1 < mycount) issue_k(v + 8);  // K prefetch for next visit

      // ---- S^T = K Q^T : A=K[key][h] from LDS, B=Q (regs) ----
      f32x4 st[2][2];  // [qs][t: 16-key tile]
#pragma unroll
      for (int qs = 0; qs < 2; ++qs)
#pragma unroll
        for (int t = 0; t < 2; ++t) st[qs][t] = (f32x4){0.f, 0.f, 0.f, 0.f};
#pragma unroll
      for (int t = 0; t < 2; ++t) {
        const bf16x8 a0 = *(const bf16x8*)&ksw[(t * 16 + col) * 72 + quad * 8];
        const bf16x8 a1 = *(const bf16x8*)&ksw[(t * 16 + col) * 72 + 32 + quad * 8];
#pragma unroll
        for (int qs = 0; qs < 2; ++qs) {
          st[qs][t] = MFMA_BF16(a0, qf[qs][0], st[qs][t]);
          st[qs][t] = MFMA_BF16(a1, qf[qs][1], st[qs][t]);
        }
      }

      // ---- p = exp2(s); causal mask on diagonal visit ----
      const bool diag = (v == qt);  // wave-uniform
      unsigned d[2][2][2];          // packed bf16 P: [qs][t][pair]
#pragma unroll
      for (int qs = 0; qs < 2; ++qs) {
        float part = 0.f;
#pragma unroll
        for (int t = 0; t < 2; ++t) {
          float pr[4];
#pragma unroll
          for (int rr = 0; rr < 4; ++rr) {
            float sv = st[qs][t][rr];
            if (diag && (t * 16 + quad * 4 + rr) > (qs * 16 + col)) sv = -1e30f;
            pr[rr] = __builtin_amdgcn_exp2f(sv);
          }
          d[qs][t][0] = pkbf(pr[0], pr[1]);
          d[qs][t][1] = pkbf(pr[2], pr[3]);
          part += bsum(d[qs][t][0]) + bsum(d[qs][t][1]);
        }
        part += __shfl_xor(part, 16);
        part += __shfl_xor(part, 32);
        osum[qs] += part;
      }

#if HAVE_MFMA16
      // ---- O^T += V^T P^T : V frags straight from vv regs, P from d regs --
#pragma unroll
      for (int t = 0; t < 2; ++t)
#pragma unroll
        for (int pg = 0; pg < 2; ++pg) {
          uint4 u = __builtin_bit_cast(uint4, vv[t * 2 + pg]);
          u32x2 l2 = {u.x, u.y}, h2 = {u.z, u.w};
          bf16x4 vlo = __builtin_bit_cast(bf16x4, l2);  // ht = 2*pg
          bf16x4 vhi = __builtin_bit_cast(bf16x4, h2);  // ht = 2*pg+1
#pragma unroll
          for (int qs = 0; qs < 2; ++qs) {
            u32x2 pd = {d[qs][t][0], d[qs][t][1]};
            bf16x4 pb = __builtin_bit_cast(bf16x4, pd);
            o[qs][2 * pg]     = MFMA16(vlo, pb, o[qs][2 * pg]);
            o[qs][2 * pg + 1] = MFMA16(vhi, pb, o[qs][2 * pg + 1]);
          }
        }
#else
      // ---- fallback: shfl-transpose P (K=32) + shfl-gather V bf16x8 ----
      bf16x8 pbf[2];
#pragma unroll
      for (int qs = 0; qs < 2; ++qs) {
        unsigned dA0 = d[qs][0][0], dB0 = d[qs][0][1];
        unsigned dA1 = d[qs][1][0], dB1 = d[qs][1][1];
        int base = ((quad & 1) << 5) + col;
        unsigned a0  = __shfl(dA0, base),      a1  = __shfl(dA1, base);
        unsigned b0  = __shfl(dB0, base),      b1  = __shfl(dB1, base);
        unsigned a0h = __shfl(dA0, base + 16), a1h = __shfl(dA1, base + 16);
        unsigned b0h = __shfl(dB0, base + 16), b1h = __shfl(dB1, base + 16);
        bool hi = quad >= 2;
        uint4 pu = make_uint4(hi ? a1 : a0, hi ? b1 : b0,
                              hi ? a1h : a0h, hi ? b1h : b0h);
        pbf[qs] = __builtin_bit_cast(bf16x8, pu);
      }
#pragma unroll
      for (int ht = 0; ht < 4; ++ht) {
        int pg = ht >> 1;
        bool odd = ht & 1;
        int L0 = ((quad & 1) * 2) * 16 + col, L1 = L0 + 16;
        uint4 u0 = __builtin_bit_cast(uint4, vv[pg]);
        uint4 u1 = __builtin_bit_cast(uint4, vv[2 + pg]);
        unsigned s0 = odd ? u0.z : u0.x, s1 = odd ? u0.w : u0.y;
        unsigned s2 = odd ? u1.z : u1.x, s3 = odd ? u1.w : u1.y;
        unsigned d0a = __shfl(s0, L0), d1a = __shfl(s1, L0);
        unsigned d2a = __shfl(s0, L1), d3a = __shfl(s1, L1);
        unsigned d0b = __shfl(s2, L0), d1b = __shfl(s3, L0);
        unsigned d2b = __shfl(s2, L1), d3b = __shfl(s3, L1);
        bool t1 = quad >= 2;
        uint4 vu = make_uint4(t1 ? d0b : d0a, t1 ? d1b : d1a,
                              t1 ? d2b : d2a, t1 ? d3b : d3a);
        bf16x8 vf8 = __builtin_bit_cast(bf16x8, vu);
#pragma unroll
        for (int qs = 0; qs < 2; ++qs)
          o[qs][ht] = MFMA_BF16(vf8, pbf[qs], o[qs][ht]);
      }
#endif
      if (i + 1 < mycount) issue_v(v + 8);  // vv free after PV: 1 visit lead
    }

    // ---- 8-way split-K combine: fold 8->4, then 4->1 (pure fp32 add) ----
    __syncthreads();
    float* comb = (float*)lds;  // 4 slots x 64 lanes x 36 floats = 36864 B
    if (wave >= 4) {
      float* p = comb + ((wave - 4) * 64 + lane) * 36;
#pragma unroll
      for (int qs = 0; qs < 2; ++qs)
#pragma unroll
        for (int ht = 0; ht < 4; ++ht)
          *(f32x4*)(p + (qs * 4 + ht) * 4) = o[qs][ht];
      p[32] = osum[0];
      p[33] = osum[1];
    }
    __syncthreads();
    if (wave < 4) {  // wave w absorbs wave w+4
      const float* p = comb + (wave * 64 + lane) * 36;
#pragma unroll
      for (int qs = 0; qs < 2; ++qs)
#pragma unroll
        for (int ht = 0; ht < 4; ++ht)
          o[qs][ht] += *(const f32x4*)(p + (qs * 4 + ht) * 4);
      osum[0] += p[32];
      osum[1] += p[33];
    }
    __syncthreads();
    if (wave >= 1 && wave < 4) {
      float* p = comb + ((wave - 1) * 64 + lane) * 36;
#pragma unroll
      for (int qs = 0; qs < 2; ++qs)
#pragma unroll
        for (int ht = 0; ht < 4; ++ht)
          *(f32x4*)(p + (qs * 4 + ht) * 4) = o[qs][ht];
      p[32] = osum[0];
      p[33] = osum[1];
    }
    __syncthreads();
    if (wave == 0) {
#pragma unroll
      for (int w = 1; w < 4; ++w) {
        const float* p = comb + ((w - 1) * 64 + lane) * 36;
#pragma unroll
        for (int qs = 0; qs < 2; ++qs)
#pragma unroll
          for (int ht = 0; ht < 4; ++ht)
            o[qs][ht] += *(const f32x4*)(p + (qs * 4 + ht) * 4);
        osum[0] += p[32];
        osum[1] += p[33];
      }
      // ---- epilogue: O^T C-layout -> packed float4 stores ----
#pragma unroll
      for (int qs = 0; qs < 2; ++qs) {
        float inv = 1.0f / osum[qs];
#pragma unroll
        for (int ht = 0; ht < 4; ++ht) {
          f32x4 val = o[qs][ht];
#pragma unroll
          for (int rr = 0; rr < 4; ++rr) val[rr] *= inv;
          *(f32x4*)(out + (qbase + qs * 16 + col) * 64 + ht * 16 + quad * 4) = val;
        }
      }
    }
  }
}

// ---------------------------------------------------------------------------
extern "C" void kernel_launch(void* const* d_in, const int* in_sizes, int n_in,
                              void* d_out, int out_size, void* d_ws, size_t ws_size,
                              hipStream_t stream) {
  const float* x  = (const float*)d_in[0];
  const float* Wk = (const float*)d_in[1];
  const float* Wq = (const float*)d_in[2];
  const float* Wv = (const float*)d_in[3];
  float* out = (float*)d_out;

  char* ws = (char*)d_ws;
  // ws layout: wtf 8 copies x 294912 B = 2.25 MB @ 0 | qb 2MB @ 4MB |
  //            kb 2MB @ 6MB | vfb 2MB @ 8MB.
  // (barrier state lives in __device__ globals -- no memset dispatch)
  short* wtf = (short*)(ws);
  short* qb  = (short*)(ws + (4 << 20));
  short* kb  = (short*)(ws + (6 << 20));
  short* vfb = (short*)(ws + (8 << 20));

  fused_kernel<<<512, 512, 0, stream>>>(x, Wk, Wq, Wv, wtf, qb, kb, vfb, out);
}